// Round 6
// baseline (458.876 us; speedup 1.0000x reference)
//
#include <hip/hip_runtime.h>
#include <math.h>

#define NROWS 262144
#define DDIM  1024
#define EEXP  64
#define NDOCS 1024
#define BM    128

typedef __attribute__((ext_vector_type(8)))  __bf16 bf16x8;
typedef __attribute__((ext_vector_type(16))) float  f32x16;
typedef unsigned short ushort_t;
typedef unsigned int   uint_t;

// ws layout:
//   Whg ushort[EEXP*DDIM], Wlg ushort[EEXP*DDIM]
//   sorted_rows int[NROWS], offsets int[NDOCS+1], cnt int[NDOCS], cursor int[NDOCS]
//   pen_sum f32, uniq f32

__global__ __launch_bounds__(1024) void init_kernel(int* cnt, float* pen_sum, float* uniq) {
    const int t = threadIdx.x;
    cnt[t] = 0;
    if (t == 0) { pen_sum[0] = 0.0f; uniq[0] = 0.0f; }
}

__global__ __launch_bounds__(256) void hist_kernel(const int* __restrict__ idx, int* __restrict__ cnt) {
    const int r = blockIdx.x * 256 + threadIdx.x;
    if (r < NROWS) atomicAdd(&cnt[idx[r]], 1);
}

__global__ __launch_bounds__(1024) void scan_kernel(const int* __restrict__ cnt,
                                                    int* __restrict__ offsets,
                                                    int* __restrict__ cursor) {
    __shared__ int sbuf[NDOCS];
    const int t = threadIdx.x;
    const int my = cnt[t];
    sbuf[t] = my;
    __syncthreads();
    for (int off = 1; off < NDOCS; off <<= 1) {
        int add = (t >= off) ? sbuf[t - off] : 0;
        __syncthreads();
        sbuf[t] += add;
        __syncthreads();
    }
    const int excl = sbuf[t] - my;
    offsets[t] = excl;
    cursor[t]  = excl;
    if (t == NDOCS - 1) offsets[NDOCS] = sbuf[t];
}

__global__ __launch_bounds__(256) void scatter_kernel(const int* __restrict__ idx,
                                                      int* __restrict__ cursor,
                                                      int* __restrict__ sorted_rows) {
    const int r = blockIdx.x * 256 + threadIdx.x;
    if (r < NROWS) {
        const int pos = atomicAdd(&cursor[idx[r]], 1);
        sorted_rows[pos] = r;
    }
}

__global__ __launch_bounds__(256) void convw_kernel(const float* __restrict__ Wg,
                                                    ushort_t* __restrict__ Whg,
                                                    ushort_t* __restrict__ Wlg) {
    const int i = blockIdx.x * 256 + threadIdx.x;
    const float wv = Wg[i];
    const uint_t b = __float_as_uint(wv);
    const float lov = wv - __uint_as_float(b & 0xFFFF0000u);
    Whg[i] = (ushort_t)(b >> 16);
    Wlg[i] = (ushort_t)(__float_as_uint(lov) >> 16);
}

#define VMCNT(N)  asm volatile("s_waitcnt vmcnt(" #N ")" ::: "memory")
#define LGKM0()   asm volatile("s_waitcnt lgkmcnt(0)" ::: "memory")
#define BAR()     do { __builtin_amdgcn_s_barrier(); asm volatile("" ::: "memory"); } while (0)
#define MEMPIN()  asm volatile("" ::: "memory")

// MFMA GEMM: BM=128, 4 waves, 32x32x16 bf16 split-hi/lo (3 products).
// x: register-direct (each lane loads only its own A-fragment rows), prefetched
// one SUPER-tile (4 K-tiles = 512 B/row) ahead -> coarse DRAM granules.
// W: reg->LDS double-buffer, 4 tiles batched per super; counted vmcnt never
// drains the x super-fetch (22/20/18/16 ledger).
struct XT { float4 a0, a1, a2, a3; };
struct XS { XT t0, t1, t2, t3; };

__global__ __launch_bounds__(256, 2) void gemm_softmax_kernel(
    const float*    __restrict__ x,
    const ushort_t* __restrict__ Whg,
    const ushort_t* __restrict__ Wlg,
    float*          __restrict__ w_out)
{
    __shared__ ushort_t whs[2][EEXP * 40];   // 5 KB each buf, row stride 40 ushort (80 B)
    __shared__ ushort_t wls[2][EEXP * 40];

    const int t   = threadIdx.x;
    const int w   = t >> 6;
    const int l   = t & 63;
    const int cl  = l & 31;     // A-row-in-wave-tile / B-col / D-col
    const int hi  = l >> 5;     // k-half selector
    const size_t br = (size_t)blockIdx.x * BM;

    // W staging coords
    const int se  = t >> 2;     // expert 0..63
    const int skq = t & 3;      // 8-ushort chunk

    const float*    xrow = x   + (br + (size_t)(w * 32 + cl)) * DDIM + 8 * hi;
    const ushort_t* wgh  = Whg + (size_t)se * DDIM + skq * 8;
    const ushort_t* wgl  = Wlg + (size_t)se * DDIM + skq * 8;

    f32x16 acc0 = {};
    f32x16 acc1 = {};
    XS xA, xB;
    uint4 wh0, wl0, wh1, wl1, wh2, wl2, wh3, wl3;

    union u8b { uint_t u[4]; bf16x8 v; };

#define LOAD_XT(DST, T) do {                                                           \
        const float* p_ = xrow + (size_t)(T) * 32;                                     \
        DST.a0 = *(const float4*)(p_);                                                 \
        DST.a1 = *(const float4*)(p_ + 4);                                             \
        DST.a2 = *(const float4*)(p_ + 16);                                            \
        DST.a3 = *(const float4*)(p_ + 20);                                            \
    } while (0)

#define LOAD_XS(S, SUP) do {                                                           \
        LOAD_XT(S.t0, 4 * (SUP) + 0);                                                  \
        LOAD_XT(S.t1, 4 * (SUP) + 1);                                                  \
        LOAD_XT(S.t2, 4 * (SUP) + 2);                                                  \
        LOAD_XT(S.t3, 4 * (SUP) + 3);                                                  \
    } while (0)

#define LOAD_WU(WH, WL, T) do {                                                        \
        WH = *(const uint4*)(wgh + (size_t)(T) * 32);                                  \
        WL = *(const uint4*)(wgl + (size_t)(T) * 32);                                  \
    } while (0)

#define WRITE_WU(SLOT, WH, WL) do {                                                    \
        *(uint4*)(whs[SLOT] + se * 40 + skq * 8) = WH;                                 \
        *(uint4*)(wls[SLOT] + se * 40 + skq * 8) = WL;                                 \
    } while (0)

#define SPLIT8(A, B, AH, AL) do {                                                      \
        const float av_[8] = {A.x, A.y, A.z, A.w, B.x, B.y, B.z, B.w};                 \
        _Pragma("unroll")                                                              \
        for (int p_ = 0; p_ < 4; ++p_) {                                               \
            const uint_t b0_ = __float_as_uint(av_[2 * p_]);                           \
            const uint_t b1_ = __float_as_uint(av_[2 * p_ + 1]);                       \
            AH.u[p_] = (b0_ >> 16) | (b1_ & 0xFFFF0000u);                              \
            const float l0_ = av_[2 * p_]     - __uint_as_float(b0_ & 0xFFFF0000u);    \
            const float l1_ = av_[2 * p_ + 1] - __uint_as_float(b1_ & 0xFFFF0000u);    \
            AL.u[p_] = (__float_as_uint(l0_) >> 16) | (__float_as_uint(l1_) & 0xFFFF0000u); \
        } } while (0)

#define COMPUTE_T(XV, SLOT) do {                                                       \
        u8b ah0, al0, ah1, al1;                                                        \
        SPLIT8(XV.a0, XV.a1, ah0, al0);                                                \
        SPLIT8(XV.a2, XV.a3, ah1, al1);                                                \
        const int ko_ = 8 * hi;                                                        \
        const bf16x8 bh00 = *(const bf16x8*)(whs[SLOT] + (cl)      * 40 +      ko_);   \
        const bf16x8 bh01 = *(const bf16x8*)(whs[SLOT] + (cl)      * 40 + 16 + ko_);   \
        const bf16x8 bh10 = *(const bf16x8*)(whs[SLOT] + (32 + cl) * 40 +      ko_);   \
        const bf16x8 bh11 = *(const bf16x8*)(whs[SLOT] + (32 + cl) * 40 + 16 + ko_);   \
        const bf16x8 bl00 = *(const bf16x8*)(wls[SLOT] + (cl)      * 40 +      ko_);   \
        const bf16x8 bl01 = *(const bf16x8*)(wls[SLOT] + (cl)      * 40 + 16 + ko_);   \
        const bf16x8 bl10 = *(const bf16x8*)(wls[SLOT] + (32 + cl) * 40 +      ko_);   \
        const bf16x8 bl11 = *(const bf16x8*)(wls[SLOT] + (32 + cl) * 40 + 16 + ko_);   \
        acc0 = __builtin_amdgcn_mfma_f32_32x32x16_bf16(ah0.v, bh00, acc0, 0, 0, 0);    \
        acc1 = __builtin_amdgcn_mfma_f32_32x32x16_bf16(ah0.v, bh10, acc1, 0, 0, 0);    \
        acc0 = __builtin_amdgcn_mfma_f32_32x32x16_bf16(ah0.v, bl00, acc0, 0, 0, 0);    \
        acc1 = __builtin_amdgcn_mfma_f32_32x32x16_bf16(ah0.v, bl10, acc1, 0, 0, 0);    \
        acc0 = __builtin_amdgcn_mfma_f32_32x32x16_bf16(al0.v, bh00, acc0, 0, 0, 0);    \
        acc1 = __builtin_amdgcn_mfma_f32_32x32x16_bf16(al0.v, bh10, acc1, 0, 0, 0);    \
        acc0 = __builtin_amdgcn_mfma_f32_32x32x16_bf16(ah1.v, bh01, acc0, 0, 0, 0);    \
        acc1 = __builtin_amdgcn_mfma_f32_32x32x16_bf16(ah1.v, bh11, acc1, 0, 0, 0);    \
        acc0 = __builtin_amdgcn_mfma_f32_32x32x16_bf16(ah1.v, bl01, acc0, 0, 0, 0);    \
        acc1 = __builtin_amdgcn_mfma_f32_32x32x16_bf16(ah1.v, bl11, acc1, 0, 0, 0);    \
        acc0 = __builtin_amdgcn_mfma_f32_32x32x16_bf16(al1.v, bh01, acc0, 0, 0, 0);    \
        acc1 = __builtin_amdgcn_mfma_f32_32x32x16_bf16(al1.v, bh11, acc1, 0, 0, 0);    \
    } while (0)

// Steady super-step S (S = 0..6): compute tiles 4S..4S+3 from XC, prefetch
// x super S+1 into XN, pipeline W tiles 4S+1..4S+4 through regs -> LDS dbuf.
#define SUPER(XC, XN, S) do {                                                          \
        LOAD_WU(wh0, wl0, 4 * (S) + 1);                                                \
        LOAD_WU(wh1, wl1, 4 * (S) + 2);                                                \
        LOAD_WU(wh2, wl2, 4 * (S) + 3);                                                \
        LOAD_WU(wh3, wl3, 4 * (S) + 4);                                                \
        MEMPIN();                                                                      \
        LOAD_XS(XN, (S) + 1);                                                          \
        MEMPIN();                                                                      \
        COMPUTE_T(XC.t0, 0); VMCNT(22); WRITE_WU(1, wh0, wl0); LGKM0(); BAR();         \
        COMPUTE_T(XC.t1, 1); VMCNT(20); WRITE_WU(0, wh1, wl1); LGKM0(); BAR();         \
        COMPUTE_T(XC.t2, 0); VMCNT(18); WRITE_WU(1, wh2, wl2); LGKM0(); BAR();         \
        COMPUTE_T(XC.t3, 1); VMCNT(16); WRITE_WU(0, wh3, wl3); LGKM0(); BAR();         \
    } while (0)

    // ---- prologue: W(0) + x super 0 ----
    LOAD_WU(wh0, wl0, 0);
    MEMPIN();
    LOAD_XS(xA, 0);
    MEMPIN();
    VMCNT(0);
    WRITE_WU(0, wh0, wl0);
    LGKM0(); BAR();

    // ---- supers 0..5 ----
    #pragma unroll 1
    for (int j = 0; j < 3; ++j) {
        SUPER(xA, xB, 2 * j);
        SUPER(xB, xA, 2 * j + 1);
    }
    // ---- super 6 (prefetches x super 7) ----
    SUPER(xA, xB, 6);
    // ---- super 7 tail: tiles 28..31, W batch 29..31, no x prefetch ----
    LOAD_WU(wh0, wl0, 29);
    LOAD_WU(wh1, wl1, 30);
    LOAD_WU(wh2, wl2, 31);
    MEMPIN();
    COMPUTE_T(xB.t0, 0); VMCNT(4); WRITE_WU(1, wh0, wl0); LGKM0(); BAR();
    COMPUTE_T(xB.t1, 1); VMCNT(2); WRITE_WU(0, wh1, wl1); LGKM0(); BAR();
    COMPUTE_T(xB.t2, 0); VMCNT(0); WRITE_WU(1, wh2, wl2); LGKM0(); BAR();
    COMPUTE_T(xB.t3, 1);

    // In-register softmax. D-layout: col = lane&31, row = (r&3) + 8*(r>>2) + 4*hi.
    const size_t orow_base = br + (size_t)w * 32;
    #pragma unroll
    for (int r = 0; r < 16; ++r) {
        const int row = (r & 3) + 8 * (r >> 2) + 4 * hi;
        const float v0 = acc0[r];
        const float v1 = acc1[r];
        float m = fmaxf(v0, v1);
        m = fmaxf(m, __shfl_xor(m, 1));
        m = fmaxf(m, __shfl_xor(m, 2));
        m = fmaxf(m, __shfl_xor(m, 4));
        m = fmaxf(m, __shfl_xor(m, 8));
        m = fmaxf(m, __shfl_xor(m, 16));
        const float e0 = __expf(v0 - m);
        const float e1 = __expf(v1 - m);
        float s = e0 + e1;
        s += __shfl_xor(s, 1);
        s += __shfl_xor(s, 2);
        s += __shfl_xor(s, 4);
        s += __shfl_xor(s, 8);
        s += __shfl_xor(s, 16);
        const float inv = 1.0f / s;
        float* wo = w_out + (orow_base + row) * EEXP;
        wo[cl]      = e0 * inv;
        wo[32 + cl] = e1 * inv;
    }
#undef LOAD_XT
#undef LOAD_XS
#undef LOAD_WU
#undef WRITE_WU
#undef SPLIT8
#undef COMPUTE_T
#undef SUPER
}

// One block per doc. Row list prefetched to LDS to break the load->load chain.
__global__ __launch_bounds__(256) void segsum_kernel(
    const float* __restrict__ w,
    const int*   __restrict__ sorted_rows,
    const int*   __restrict__ offsets,
    float*       __restrict__ pen_sum,
    float*       __restrict__ uniq)
{
    __shared__ int rows_s[512];
    __shared__ float ls1[4][64], ls2[4][64];

    const int d  = blockIdx.x;
    const int t  = threadIdx.x;
    const int e  = t & 63;
    const int rg = t >> 6;
    const int start = offsets[d];
    const int end   = offsets[d + 1];
    const int n     = end - start;

    for (int i = t; i < n && i < 512; i += 256) rows_s[i] = sorted_rows[start + i];
    __syncthreads();

    float s1 = 0.0f, s2 = 0.0f;
    for (int i = rg; i < n; i += 4) {
        const int row = (i < 512) ? rows_s[i] : sorted_rows[start + i];
        const float v = w[(size_t)row * EEXP + e];
        s1 += v;
        s2 += v * v;
    }

    ls1[rg][e] = s1;
    ls2[rg][e] = s2;
    __syncthreads();

    if (t < 64) {
        const float a = ls1[0][e] + ls1[1][e] + ls1[2][e] + ls1[3][e];
        const float b = ls2[0][e] + ls2[1][e] + ls2[2][e] + ls2[3][e];
        const float safe = fmaxf((float)n, 1.0f);
        float contrib = b - a * a / safe;
        #pragma unroll
        for (int off = 32; off > 0; off >>= 1)
            contrib += __shfl_down(contrib, off);
        if (e == 0) {
            if (n > 1) atomicAdd(pen_sum, contrib / (safe * (float)EEXP));
            if (n > 0) atomicAdd(uniq, 1.0f);
        }
    }
}

__global__ void final_kernel(const float* __restrict__ pen_sum,
                             const float* __restrict__ uniq,
                             float* __restrict__ pen_out) {
    pen_out[0] = pen_sum[0] / uniq[0];
}

extern "C" void kernel_launch(void* const* d_in, const int* in_sizes, int n_in,
                              void* d_out, int out_size, void* d_ws, size_t ws_size,
                              hipStream_t stream) {
    const float* x   = (const float*)d_in[0];
    const int*   idx = (const int*)d_in[1];
    const float* Wg  = (const float*)d_in[2];

    float* out   = (float*)d_out;
    float* w_out = out;                                  // NROWS*EEXP floats
    float* pen   = out + (size_t)NROWS * EEXP;           // 1 float

    ushort_t* Whg = (ushort_t*)d_ws;
    ushort_t* Wlg = Whg + (size_t)EEXP * DDIM;
    int* sorted_rows = (int*)(Wlg + (size_t)EEXP * DDIM);
    int* offsets     = sorted_rows + NROWS;
    int* cnt         = offsets + NDOCS + 1;
    int* cursor      = cnt + NDOCS;
    float* pen_sum   = (float*)(cursor + NDOCS);
    float* uniq      = pen_sum + 1;

    init_kernel<<<1, 1024, 0, stream>>>(cnt, pen_sum, uniq);
    hist_kernel<<<NROWS / 256, 256, 0, stream>>>(idx, cnt);
    scan_kernel<<<1, 1024, 0, stream>>>(cnt, offsets, cursor);
    scatter_kernel<<<NROWS / 256, 256, 0, stream>>>(idx, cursor, sorted_rows);
    convw_kernel<<<(EEXP * DDIM) / 256, 256, 0, stream>>>(Wg, Whg, Wlg);
    gemm_softmax_kernel<<<NROWS / BM, 256, 0, stream>>>(x, Whg, Wlg, w_out);
    segsum_kernel<<<NDOCS, 256, 0, stream>>>(w_out, sorted_rows, offsets, pen_sum, uniq);
    final_kernel<<<1, 1, 0, stream>>>(pen_sum, uniq, pen);
}